// Round 6
// baseline (273.012 us; speedup 1.0000x reference)
//
#include <hip/hip_runtime.h>
#include <math.h>

#define NJ 25          // joints (voxel channels)
#define NJP 32         // padded channel stride in transposed layout (128B, float4-aligned)
#define VD 32
#define VH 128
#define VW 128
#define TEMP 20.0f
#define NEGINF (-10000.0f)
#define DHW (VD*VH*VW)        // 524288
#define NCELL 4096            // 16^3 morton cells for the point sort
#define TINV_FLOATS 256

// workspace arena (floats): [tinv 256 | hist 4096 | offs 4096 | perm N | vt 16.78M]
// small buffers FIRST so sort availability == VT availability (no silent skip).

// ---------------- Kernel A: invert init-bone transforms + zero the sort histogram ----
__global__ void setup_kernel(const float* __restrict__ tfs,
                             const int* __restrict__ bones,
                             float* __restrict__ tinv,
                             int* __restrict__ hist, int ni) {
    int b = blockIdx.x, t = threadIdx.x;
    if (b == 0) {
        if (t >= ni) return;
        const float* T = tfs + (size_t)bones[t] * 16;
        double r00=T[0], r01=T[1], r02=T[2],  tx=T[3];
        double r10=T[4], r11=T[5], r12=T[6],  ty=T[7];
        double r20=T[8], r21=T[9], r22=T[10], tz=T[11];
        double c00 = r11*r22 - r12*r21;
        double c01 = r12*r20 - r10*r22;
        double c02 = r10*r21 - r11*r20;
        double det = r00*c00 + r01*c01 + r02*c02;
        double id  = 1.0/det;
        double i00 = c00*id;
        double i01 = (r02*r21 - r01*r22)*id;
        double i02 = (r01*r12 - r02*r11)*id;
        double i10 = c01*id;
        double i11 = (r00*r22 - r02*r20)*id;
        double i12 = (r02*r10 - r00*r12)*id;
        double i20 = c02*id;
        double i21 = (r01*r20 - r00*r21)*id;
        double i22 = (r00*r11 - r01*r10)*id;
        double itx = -(i00*tx + i01*ty + i02*tz);
        double ity = -(i10*tx + i11*ty + i12*tz);
        double itz = -(i20*tx + i21*ty + i22*tz);
        float* o = tinv + t*12;
        o[0]=(float)i00; o[1]=(float)i01; o[2] =(float)i02; o[3] =(float)itx;
        o[4]=(float)i10; o[5]=(float)i11; o[6] =(float)i12; o[7] =(float)ity;
        o[8]=(float)i20; o[9]=(float)i21; o[10]=(float)i22; o[11]=(float)itz;
    } else {
        int g = (b-1)*256 + t;
        if (g < NCELL) hist[g] = 0;
    }
}

// ---------------- Kernel B: transpose [J][D][H][W] -> [D][H][W][NJP], float4 both sides
__global__ __launch_bounds__(256) void transpose_vox_kernel(const float* __restrict__ vox,
                                                            float* __restrict__ vt) {
    __shared__ float lds[NJ*129];
    int row = blockIdx.x;                  // z*VH + y  (0..4095)
    int t = threadIdx.x;
    const float4* v4 = (const float4*)vox;
    for (int idx = t; idx < NJ*32; idx += 256) {       // 800 float4 loads
        int j  = idx >> 5;
        int x4 = idx & 31;
        float4 v = v4[(size_t)j*(DHW/4) + (size_t)row*32 + x4];
        float* l = &lds[j*129 + x4*4];
        l[0]=v.x; l[1]=v.y; l[2]=v.z; l[3]=v.w;
    }
    __syncthreads();
    float4* out4 = (float4*)(vt + (size_t)row * (VW*NJP));
    for (int idx = t; idx < (VW*NJP)/4; idx += 256) {  // 1024 float4 stores
        int xx = idx >> 3;
        int jq = (idx & 7) * 4;
        float4 o;
        o.x = (jq+0 < NJ) ? lds[(jq+0)*129 + xx] : 0.0f;
        o.y = (jq+1 < NJ) ? lds[(jq+1)*129 + xx] : 0.0f;
        o.z = (jq+2 < NJ) ? lds[(jq+2)*129 + xx] : 0.0f;
        o.w = (jq+3 < NJ) ? lds[(jq+3)*129 + xx] : 0.0f;
        out4[idx] = o;
    }
}

// ---------------- Sort kernels: morton-cell counting sort of points ----------------
__device__ __forceinline__ int cell_of(float v) {       // [-1,1] -> 0..15
    int c = (int)((v + 1.0f) * 8.0f);
    return min(max(c, 0), 15);
}
__device__ __forceinline__ int morton12(int ix, int iy, int iz) {
    int m = 0;
    #pragma unroll
    for (int b = 0; b < 4; ++b)
        m |= (((ix>>b)&1)<<(3*b)) | (((iy>>b)&1)<<(3*b+1)) | (((iz>>b)&1)<<(3*b+2));
    return m;
}
__global__ void hist_kernel(const float* __restrict__ x, int* __restrict__ hist, int N) {
    int g = blockIdx.x*256 + threadIdx.x;
    if (g >= N) return;
    int m = morton12(cell_of(x[g*3+0]), cell_of(x[g*3+1]), cell_of(x[g*3+2]));
    atomicAdd(&hist[m], 1);
}
__global__ __launch_bounds__(1024) void scan_kernel(const int* __restrict__ hist,
                                                    int* __restrict__ offs) {
    __shared__ int part[1024];
    int t = threadIdx.x;
    int4 h = ((const int4*)hist)[t];
    int s = h.x + h.y + h.z + h.w;
    part[t] = s;
    __syncthreads();
    for (int off = 1; off < 1024; off <<= 1) {
        int v = (t >= off) ? part[t-off] : 0;
        __syncthreads();
        part[t] += v;
        __syncthreads();
    }
    int excl = part[t] - s;
    offs[4*t+0] = excl;
    offs[4*t+1] = excl + h.x;
    offs[4*t+2] = excl + h.x + h.y;
    offs[4*t+3] = excl + h.x + h.y + h.z;
}
__global__ void scatter_kernel(const float* __restrict__ x, int* __restrict__ offs,
                               int* __restrict__ perm, int N) {
    int g = blockIdx.x*256 + threadIdx.x;
    if (g >= N) return;
    int m = morton12(cell_of(x[g*3+0]), cell_of(x[g*3+1]), cell_of(x[g*3+2]));
    int pos = atomicAdd(&offs[m], 1);
    perm[pos] = g;
}

// ---------------- Kernel C: main per-point deformer ----------------
__device__ __forceinline__ float f4g(const float4 v, int k) {
    return k==0 ? v.x : k==1 ? v.y : k==2 ? v.z : v.w;
}

// per-channel: softmax numerator + folded warp applied to xc_h DIRECTLY:
// wx += ev*(M row0 . xc_h) etc. -> 3 accumulators instead of 12 E regs.
// M read from global tfs at compile-time offsets -> scalar-cache s_load path.
#define CH_BODY(jj, vv) do {                                              \
    float ev = __expf(TEMP * (vv));                                       \
    s_sum += ev;                                                          \
    const float* M_ = &tfs[(jj)*16];                                      \
    wx += ev*(M_[0]*cx + M_[1]*cy + M_[2] *cz + M_[3]);                   \
    wy += ev*(M_[4]*cx + M_[5]*cy + M_[6] *cz + M_[7]);                   \
    wz += ev*(M_[8]*cx + M_[9]*cy + M_[10]*cz + M_[11]);                  \
    if ((jj) < 15) myE[curOff + (jj)] = ev;                               \
} while (0)

// 4 threads per point; thread `sub` handles inits i = sub, sub+4, ...
// Softmax numerators + invs live in per-thread LDS double-slots (stride 33);
// winner's xc recomputed from bestIdx at the end (bit-identical FMAs).
// NOTE: plain __launch_bounds__(256) — (256,4) forced VGPR=64 + 577MB spill (round 4).
template<bool VT>
__global__ __launch_bounds__(256) void deformer_kernel(
        const float* __restrict__ x,
        const float* __restrict__ tfs,
        const float* __restrict__ vsrc,
        const float* __restrict__ tinv,
        const int* __restrict__ perm,
        float* __restrict__ out, int N, int ni) {
    __shared__ float s_feat[256*33];           // 33 KB: two 16-float slots + pad per thread
    int t   = threadIdx.x;

    // bijective XCD chunk-swizzle: each XCD gets a contiguous morton range
    int nwg = gridDim.x;
    int q = nwg >> 3, r = nwg & 7;
    int xcd = blockIdx.x & 7, blk = blockIdx.x >> 3;
    int lb = (xcd < r ? xcd*(q+1) : r*(q+1) + (xcd-r)*q) + blk;

    int ns  = lb*64 + (t >> 2);                // 64 points per block
    int sub = t & 3;
    if (ns >= N) return;
    int n = perm ? perm[ns] : ns;

    float px = x[n*3+0], py = x[n*3+1], pz = x[n*3+2];
    float* myE = &s_feat[t*33];

    float bestD = -3.0e38f;
    int   bestIdx = 0x7fffffff;
    int   curOff = 0, bestOff = 0;

    #pragma unroll 1
    for (int i = sub; i < ni; i += 4) {
        const float* Ti = &tinv[i*12];
        float cx = Ti[0]*px + Ti[1]*py + Ti[2] *pz + Ti[3];
        float cy = Ti[4]*px + Ti[5]*py + Ti[6] *pz + Ti[7];
        float cz = Ti[8]*px + Ti[9]*py + Ti[10]*pz + Ti[11];

        float gx = fminf(fmaxf((cx + 1.0f) * (0.5f*(VW-1)), 0.0f), (float)(VW-1));
        float gy = fminf(fmaxf((cy + 1.0f) * (0.5f*(VH-1)), 0.0f), (float)(VH-1));
        float gz = fminf(fmaxf((cz + 1.0f) * (0.5f*(VD-1)), 0.0f), (float)(VD-1));
        int x0 = (int)gx, y0 = (int)gy, z0 = (int)gz;
        int x1 = min(x0+1, VW-1), y1 = min(y0+1, VH-1), z1 = min(z0+1, VD-1);
        float fx = gx - (float)x0, fy = gy - (float)y0, fz = gz - (float)z0;
        float ax = 1.0f - fx, ay = 1.0f - fy, az = 1.0f - fz;
        float w000 = ax*ay*az, w001 = fx*ay*az, w010 = ax*fy*az, w011 = fx*fy*az;
        float w100 = ax*ay*fz, w101 = fx*ay*fz, w110 = ax*fy*fz, w111 = fx*fy*fz;

        float s_sum = 0.0f;
        float wx = 0.0f, wy = 0.0f, wz = 0.0f;

        if (VT) {
            int o000 = ((z0*VH + y0)*VW + x0) * NJP;
            int dz = (z1 - z0) * (VH*VW*NJP);
            int dy = (y1 - y0) * (VW*NJP);
            int dx = (x1 - x0) * NJP;
            int o001 = o000 + dx,      o010 = o000 + dy,      o011 = o000 + dy + dx;
            int o100 = o000 + dz,      o101 = o000 + dz + dx;
            int o110 = o000 + dz + dy, o111 = o000 + dz + dy + dx;

            #pragma unroll
            for (int j4 = 0; j4 < 7; ++j4) {
                const int jb = j4*4;
                float4 a000 = *(const float4*)&vsrc[o000 + jb];
                float4 a001 = *(const float4*)&vsrc[o001 + jb];
                float4 a010 = *(const float4*)&vsrc[o010 + jb];
                float4 a011 = *(const float4*)&vsrc[o011 + jb];
                float4 a100 = *(const float4*)&vsrc[o100 + jb];
                float4 a101 = *(const float4*)&vsrc[o101 + jb];
                float4 a110 = *(const float4*)&vsrc[o110 + jb];
                float4 a111 = *(const float4*)&vsrc[o111 + jb];
                #pragma unroll
                for (int k = 0; k < 4; ++k) {
                    const int j = jb + k;
                    if (j < NJ) {
                        float v = f4g(a000,k)*w000 + f4g(a001,k)*w001
                                + f4g(a010,k)*w010 + f4g(a011,k)*w011
                                + f4g(a100,k)*w100 + f4g(a101,k)*w101
                                + f4g(a110,k)*w110 + f4g(a111,k)*w111;
                        CH_BODY(j, v);
                    }
                }
            }
        } else {
            int b000 = (z0*VH + y0)*VW + x0;
            int dz = (z1 - z0) * (VH*VW);
            int dy = (y1 - y0) * VW;
            int dx = (x1 - x0);
            #pragma unroll
            for (int j = 0; j < NJ; ++j) {
                const float* vj = vsrc + (size_t)j*DHW + b000;
                float v = vj[0]*w000        + vj[dx]*w001
                        + vj[dy]*w010       + vj[dy+dx]*w011
                        + vj[dz]*w100       + vj[dz+dx]*w101
                        + vj[dz+dy]*w110    + vj[dz+dy+dx]*w111;
                CH_BODY(j, v);
            }
        }

        float invs = 1.0f / s_sum;
        float dxp = wx*invs - px, dyp = wy*invs - py, dzp = wz*invs - pz;
        float err = sqrtf(dxp*dxp + dyp*dyp + dzp*dzp);
        float d = (err < 0.1f) ? -err : NEGINF;

        if (d > bestD || (d == bestD && i < bestIdx)) {
            bestD = d; bestIdx = i;
            myE[curOff + 15] = invs;          // park invs with the winning e-slot
            bestOff = curOff; curOff ^= 16;   // protect winning slot
        }
    }

    // combine the 4 candidates — argmax with first-index tie-break
    float od = __shfl_xor(bestD, 1); int oi = __shfl_xor(bestIdx, 1);
    if (od > bestD || (od == bestD && oi < bestIdx)) { bestD = od; bestIdx = oi; }
    od = __shfl_xor(bestD, 2); oi = __shfl_xor(bestIdx, 2);
    if (od > bestD || (od == bestD && oi < bestIdx)) { bestD = od; bestIdx = oi; }

    // exactly one of the 4 lanes owns the winning candidate's payload
    if (sub == (bestIdx & 3)) {
        // recompute winner's xc (bit-identical: same inputs, same op order)
        const float* Ti = &tinv[bestIdx*12];
        float cx = Ti[0]*px + Ti[1]*py + Ti[2] *pz + Ti[3];
        float cy = Ti[4]*px + Ti[5]*py + Ti[6] *pz + Ti[7];
        float cz = Ti[8]*px + Ti[9]*py + Ti[10]*pz + Ti[11];
        float invs = myE[bestOff + 15];
        float* o_d = out;                       // [N]
        float* o_f = out + N;                   // [N,15]
        float* o_m = out + (size_t)N*16;        // [N]
        float* o_w = out + (size_t)N*17;        // [N,3]
        o_d[n] = bestD;
        #pragma unroll
        for (int k = 0; k < 15; ++k) o_f[(size_t)n*15 + k] = myE[bestOff + k] * invs;
        o_m[n] = (bestD > -9999.0f) ? 1.0f : 0.0f;
        o_w[n*3+0] = cx; o_w[n*3+1] = cy; o_w[n*3+2] = cz;
    }
}

extern "C" void kernel_launch(void* const* d_in, const int* in_sizes, int n_in,
                              void* d_out, int out_size, void* d_ws, size_t ws_size,
                              hipStream_t stream) {
    const float* x     = (const float*)d_in[0];   // [1,N,3]
    const float* tfs   = (const float*)d_in[1];   // [1,25,4,4]
    const float* vox   = (const float*)d_in[2];   // [1,25,32,128,128]
    const int*   bones = (const int*)  d_in[3];   // [14]
    int N  = in_sizes[0] / 3;
    int ni = in_sizes[3];

    float* ws = (float*)d_ws;
    // arena (floats): [tinv 256 | hist 4096 | offs 4096 | perm N | vt 16.78M]
    size_t vt_off    = (size_t)TINV_FLOATS + NCELL*2 + (size_t)N;   // 16B-aligned for N%4==0
    size_t vt_floats = (size_t)DHW * NJP;
    size_t need_all  = vt_off + vt_floats;

    float* tinv = ws;
    int*   hist = (int*)(ws + TINV_FLOATS);
    int*   offs = hist + NCELL;
    int*   perm = offs + NCELL;
    float* vt   = ws + vt_off;

    bool useVT = ws_size >= need_all * sizeof(float);
    int nblk = (N + 63) / 64;

    hipLaunchKernelGGL(setup_kernel, dim3(1 + NCELL/256), dim3(256), 0, stream,
                       tfs, bones, tinv, hist, ni);
    if (useVT) {
        hipLaunchKernelGGL(transpose_vox_kernel, dim3(VD*VH), dim3(256), 0, stream,
                           vox, vt);
        hipLaunchKernelGGL(hist_kernel, dim3((N+255)/256), dim3(256), 0, stream, x, hist, N);
        hipLaunchKernelGGL(scan_kernel, dim3(1), dim3(1024), 0, stream, hist, offs);
        hipLaunchKernelGGL(scatter_kernel, dim3((N+255)/256), dim3(256), 0, stream, x, offs, perm, N);
        hipLaunchKernelGGL((deformer_kernel<true>), dim3(nblk), dim3(256), 0, stream,
                           x, tfs, vt, tinv, perm, (float*)d_out, N, ni);
    } else {
        hipLaunchKernelGGL((deformer_kernel<false>), dim3(nblk), dim3(256), 0, stream,
                           x, tfs, vox, tinv, (const int*)nullptr,
                           (float*)d_out, N, ni);
    }
}

// Round 9
// 229.684 us; speedup vs baseline: 1.1886x; 1.1886x over previous
//
#include <hip/hip_runtime.h>
#include <math.h>

#define NJ 25          // joints (voxel channels)
#define NJP 32         // padded channel stride in transposed layout (128B-aligned)
#define VD 32
#define VH 128
#define VW 128
#define TEMP 20.0f
#define NEGINF (-10000.0f)
#define DHW (VD*VH*VW)        // 524288
#define NCELL 4096            // 16^3 morton cells for the point sort
#define TINV_FLOATS 256

// workspace arena (floats): [tinv 256 | hist 4096 | offs 4096 | perm N | vt 16.78M]

// ---------------- sort helpers ----------------
__device__ __forceinline__ int cell_of(float v) {       // [-1,1] -> 0..15
    int c = (int)((v + 1.0f) * 8.0f);
    return min(max(c, 0), 15);
}
__device__ __forceinline__ int morton12(int ix, int iy, int iz) {
    int m = 0;
    #pragma unroll
    for (int b = 0; b < 4; ++b)
        m |= (((ix>>b)&1)<<(3*b)) | (((iy>>b)&1)<<(3*b+1)) | (((iz>>b)&1)<<(3*b+2));
    return m;
}

// ---------------- Kernel A: invert init-bone transforms + zero the sort histogram ----
__global__ void setup_kernel(const float* __restrict__ tfs,
                             const int* __restrict__ bones,
                             float* __restrict__ tinv,
                             int* __restrict__ hist, int ni) {
    int b = blockIdx.x, t = threadIdx.x;
    if (b == 0) {
        if (t >= ni) return;
        const float* T = tfs + (size_t)bones[t] * 16;
        double r00=T[0], r01=T[1], r02=T[2],  tx=T[3];
        double r10=T[4], r11=T[5], r12=T[6],  ty=T[7];
        double r20=T[8], r21=T[9], r22=T[10], tz=T[11];
        double c00 = r11*r22 - r12*r21;
        double c01 = r12*r20 - r10*r22;
        double c02 = r10*r21 - r11*r20;
        double det = r00*c00 + r01*c01 + r02*c02;
        double id  = 1.0/det;
        double i00 = c00*id;
        double i01 = (r02*r21 - r01*r22)*id;
        double i02 = (r01*r12 - r02*r11)*id;
        double i10 = c01*id;
        double i11 = (r00*r22 - r02*r20)*id;
        double i12 = (r02*r10 - r00*r12)*id;
        double i20 = c02*id;
        double i21 = (r01*r20 - r00*r21)*id;
        double i22 = (r00*r11 - r01*r10)*id;
        double itx = -(i00*tx + i01*ty + i02*tz);
        double ity = -(i10*tx + i11*ty + i12*tz);
        double itz = -(i20*tx + i21*ty + i22*tz);
        float* o = tinv + t*12;
        o[0]=(float)i00; o[1]=(float)i01; o[2] =(float)i02; o[3] =(float)itx;
        o[4]=(float)i10; o[5]=(float)i11; o[6] =(float)i12; o[7] =(float)ity;
        o[8]=(float)i20; o[9]=(float)i21; o[10]=(float)i22; o[11]=(float)itz;
    } else if (hist != nullptr) {
        int g = (b-1)*256 + t;
        if (g < NCELL) hist[g] = 0;
    }
}

// ---------------- Kernel B: transpose [J][D][H][W] -> [D][H][W][NJP] + fused hist ----
__global__ __launch_bounds__(256) void transpose_vox_kernel(const float* __restrict__ vox,
                                                            float* __restrict__ vt,
                                                            const float* __restrict__ x,
                                                            int* __restrict__ hist, int N) {
    __shared__ float lds[NJ*129];
    int row = blockIdx.x;                  // z*VH + y  (0..4095)
    int t = threadIdx.x;
    const float4* v4 = (const float4*)vox;
    for (int idx = t; idx < NJ*32; idx += 256) {       // 800 float4 loads
        int j  = idx >> 5;
        int x4 = idx & 31;
        float4 v = v4[(size_t)j*(DHW/4) + (size_t)row*32 + x4];
        float* l = &lds[j*129 + x4*4];
        l[0]=v.x; l[1]=v.y; l[2]=v.z; l[3]=v.w;
    }
    __syncthreads();
    float4* out4 = (float4*)(vt + (size_t)row * (VW*NJP));
    for (int idx = t; idx < (VW*NJP)/4; idx += 256) {  // 1024 float4 stores
        int xx = idx >> 3;
        int jq = (idx & 7) * 4;
        float4 o;
        o.x = (jq+0 < NJ) ? lds[(jq+0)*129 + xx] : 0.0f;
        o.y = (jq+1 < NJ) ? lds[(jq+1)*129 + xx] : 0.0f;
        o.z = (jq+2 < NJ) ? lds[(jq+2)*129 + xx] : 0.0f;
        o.w = (jq+3 < NJ) ? lds[(jq+3)*129 + xx] : 0.0f;
        out4[idx] = o;
    }
    // fused morton histogram (disjoint memory; setup_kernel zeroed hist earlier)
    for (int g = blockIdx.x*256 + t; g < N; g += gridDim.x*256) {
        int m = morton12(cell_of(x[g*3+0]), cell_of(x[g*3+1]), cell_of(x[g*3+2]));
        atomicAdd(&hist[m], 1);
    }
}

// ---------------- scan + scatter (counting sort) ----------------
__global__ __launch_bounds__(1024) void scan_kernel(const int* __restrict__ hist,
                                                    int* __restrict__ offs) {
    __shared__ int part[1024];
    int t = threadIdx.x;
    int4 h = ((const int4*)hist)[t];
    int s = h.x + h.y + h.z + h.w;
    part[t] = s;
    __syncthreads();
    for (int off = 1; off < 1024; off <<= 1) {
        int v = (t >= off) ? part[t-off] : 0;
        __syncthreads();
        part[t] += v;
        __syncthreads();
    }
    int excl = part[t] - s;
    offs[4*t+0] = excl;
    offs[4*t+1] = excl + h.x;
    offs[4*t+2] = excl + h.x + h.y;
    offs[4*t+3] = excl + h.x + h.y + h.z;
}
__global__ void scatter_kernel(const float* __restrict__ x, int* __restrict__ offs,
                               int* __restrict__ perm, int N) {
    int g = blockIdx.x*256 + threadIdx.x;
    if (g >= N) return;
    int m = morton12(cell_of(x[g*3+0]), cell_of(x[g*3+1]), cell_of(x[g*3+2]));
    int pos = atomicAdd(&offs[m], 1);
    perm[pos] = g;
}

// ---------------- Kernel C: channel-parallel deformer ----------------
// One (point,init) pair per HALF-WAVE: lane j ( = tid&31 ) owns voxel channel j.
// Corner reads are fully coalesced 128B wave-ops (4 cache lines per op instead of
// ~64 with the old lane-per-pair gather — kills the TA line-serialization).
// M_j staged once into 12 registers per lane; softmax numerator kept in ONE register
// (bestEv) per lane; s_sum / warp-fold reduced by width-32 shfl butterflies. LDS = 0.
template<bool VT>
__global__ __launch_bounds__(256) void deformer_cp_kernel(
        const float* __restrict__ x,
        const float* __restrict__ tfs,
        const float* __restrict__ vsrc,
        const float* __restrict__ tinv,
        const int* __restrict__ perm,
        float* __restrict__ out, int N, int ni) {
    int t = threadIdx.x;
    int j = t & 31;                        // channel lane

    // bijective XCD chunk-swizzle (nblk = 8192 -> r == 0, exact chunks)
    int nwg = gridDim.x;
    int q = nwg >> 3, r = nwg & 7;
    int xcd = blockIdx.x & 7, blk = blockIdx.x >> 3;
    int lb = (xcd < r ? xcd*(q+1) : r*(q+1) + (xcd-r)*q) + blk;

    int ns = lb*8 + (t >> 5);              // 8 points (half-waves) per 256-thr block
    if (ns >= N) return;
    int n = perm ? perm[ns] : ns;

    float px = x[n*3+0], py = x[n*3+1], pz = x[n*3+2];

    int jj = (j < NJ) ? j : (NJ-1);
    const float* Mj = tfs + jj*16;         // one-time per-lane stage of joint row-block
    float m0=Mj[0], m1=Mj[1], m2 =Mj[2],  m3 =Mj[3];
    float m4=Mj[4], m5=Mj[5], m6 =Mj[6],  m7 =Mj[7];
    float m8=Mj[8], m9=Mj[9], m10=Mj[10], m11=Mj[11];
    bool chv = (j < NJ);

    float bestD = -3.0e38f; int bestIdx = 0;
    float bestEv = 0.0f, bestInvs = 1.0f;

    #pragma unroll 1
    for (int i = 0; i < ni; ++i) {
        const float* Ti = &tinv[i*12];     // loop-uniform -> scalar loads
        float cx = Ti[0]*px + Ti[1]*py + Ti[2] *pz + Ti[3];
        float cy = Ti[4]*px + Ti[5]*py + Ti[6] *pz + Ti[7];
        float cz = Ti[8]*px + Ti[9]*py + Ti[10]*pz + Ti[11];

        float gx = fminf(fmaxf((cx + 1.0f) * (0.5f*(VW-1)), 0.0f), (float)(VW-1));
        float gy = fminf(fmaxf((cy + 1.0f) * (0.5f*(VH-1)), 0.0f), (float)(VH-1));
        float gz = fminf(fmaxf((cz + 1.0f) * (0.5f*(VD-1)), 0.0f), (float)(VD-1));
        int x0 = (int)gx, y0 = (int)gy, z0 = (int)gz;
        int x1 = min(x0+1, VW-1), y1 = min(y0+1, VH-1), z1 = min(z0+1, VD-1);
        float fx = gx - (float)x0, fy = gy - (float)y0, fz = gz - (float)z0;
        float ax = 1.0f - fx, ay = 1.0f - fy, az = 1.0f - fz;
        float w000 = ax*ay*az, w001 = fx*ay*az, w010 = ax*fy*az, w011 = fx*fy*az;
        float w100 = ax*ay*fz, w101 = fx*ay*fz, w110 = ax*fy*fz, w111 = fx*fy*fz;

        float v000,v001,v010,v011,v100,v101,v110,v111;
        if (VT) {
            int o   = ((z0*VH + y0)*VW + x0)*NJP + j;    // coalesced over j
            int dz  = (z1 - z0) * (VH*VW*NJP);
            int dy  = (y1 - y0) * (VW*NJP);
            int dxo = (x1 - x0) * NJP;
            v000 = vsrc[o];          v001 = vsrc[o+dxo];
            v010 = vsrc[o+dy];       v011 = vsrc[o+dy+dxo];
            v100 = vsrc[o+dz];       v101 = vsrc[o+dz+dxo];
            v110 = vsrc[o+dz+dy];    v111 = vsrc[o+dz+dy+dxo];
        } else {
            int o   = jj*DHW + (z0*VH + y0)*VW + x0;     // fallback: original layout
            int dz  = (z1 - z0) * (VH*VW);
            int dy  = (y1 - y0) * VW;
            int dxo = (x1 - x0);
            v000 = vsrc[o];          v001 = vsrc[o+dxo];
            v010 = vsrc[o+dy];       v011 = vsrc[o+dy+dxo];
            v100 = vsrc[o+dz];       v101 = vsrc[o+dz+dxo];
            v110 = vsrc[o+dz+dy];    v111 = vsrc[o+dz+dy+dxo];
        }
        // same accumulation order as the passing r5 kernel
        float v = v000*w000 + v001*w001 + v010*w010 + v011*w011
                + v100*w100 + v101*w101 + v110*w110 + v111*w111;

        float ev = chv ? __expf(TEMP * v) : 0.0f;        // pad lanes contribute 0
        float mx = m0*cx + m1*cy + m2 *cz + m3;
        float my_= m4*cx + m5*cy + m6 *cz + m7;
        float mz = m8*cx + m9*cy + m10*cz + m11;

        float rs = ev, rx = ev*mx, ry = ev*my_, rz = ev*mz;
        #pragma unroll
        for (int mk = 1; mk < 32; mk <<= 1) {
            rs += __shfl_xor(rs, mk, 32);
            rx += __shfl_xor(rx, mk, 32);
            ry += __shfl_xor(ry, mk, 32);
            rz += __shfl_xor(rz, mk, 32);
        }
        float invs = 1.0f / rs;
        float dxp = rx*invs - px, dyp = ry*invs - py, dzp = rz*invs - pz;
        float err = sqrtf(dxp*dxp + dyp*dyp + dzp*dzp);
        float d = (err < 0.1f) ? -err : NEGINF;

        if (d > bestD) {                   // strict > + ascending i = first-index tie-break
            bestD = d; bestIdx = i; bestEv = ev; bestInvs = invs;
        }
    }

    float* o_d = out;                       // [N]
    float* o_f = out + N;                   // [N,15]
    float* o_m = out + (size_t)N*16;        // [N]
    float* o_w = out + (size_t)N*17;        // [N,3]
    if (j < 15) {
        o_f[(size_t)n*15 + j] = bestEv * bestInvs;
    } else if (j == 15) {
        o_d[n] = bestD;
    } else if (j == 16) {
        o_m[n] = (bestD > -9999.0f) ? 1.0f : 0.0f;
    } else if (j < 20) {
        int rr = j - 17;                    // winner xc, one row per lane
        const float* Tr = &tinv[bestIdx*12 + rr*4];
        o_w[(size_t)n*3 + rr] = Tr[0]*px + Tr[1]*py + Tr[2]*pz + Tr[3];
    }
}

extern "C" void kernel_launch(void* const* d_in, const int* in_sizes, int n_in,
                              void* d_out, int out_size, void* d_ws, size_t ws_size,
                              hipStream_t stream) {
    const float* x     = (const float*)d_in[0];   // [1,N,3]
    const float* tfs   = (const float*)d_in[1];   // [1,25,4,4]
    const float* vox   = (const float*)d_in[2];   // [1,25,32,128,128]
    const int*   bones = (const int*)  d_in[3];   // [14]
    int N  = in_sizes[0] / 3;
    int ni = in_sizes[3];

    float* ws = (float*)d_ws;
    // arena (floats): [tinv 256 | hist 4096 | offs 4096 | perm N | vt 16.78M]
    size_t vt_off    = (size_t)TINV_FLOATS + NCELL*2 + (size_t)N;
    size_t vt_floats = (size_t)DHW * NJP;
    size_t need_all  = vt_off + vt_floats;

    float* tinv = ws;
    int*   hist = (int*)(ws + TINV_FLOATS);
    int*   offs = hist + NCELL;
    int*   perm = offs + NCELL;
    float* vt   = ws + vt_off;

    bool useVT = ws_size >= need_all * sizeof(float);
    int nblk = (N + 7) / 8;                 // 8 points per 256-thread block

    if (useVT) {
        hipLaunchKernelGGL(setup_kernel, dim3(1 + NCELL/256), dim3(256), 0, stream,
                           tfs, bones, tinv, hist, ni);
        hipLaunchKernelGGL(transpose_vox_kernel, dim3(VD*VH), dim3(256), 0, stream,
                           vox, vt, x, hist, N);
        hipLaunchKernelGGL(scan_kernel, dim3(1), dim3(1024), 0, stream, hist, offs);
        hipLaunchKernelGGL(scatter_kernel, dim3((N+255)/256), dim3(256), 0, stream,
                           x, offs, perm, N);
        hipLaunchKernelGGL((deformer_cp_kernel<true>), dim3(nblk), dim3(256), 0, stream,
                           x, tfs, vt, tinv, perm, (float*)d_out, N, ni);
    } else {
        hipLaunchKernelGGL(setup_kernel, dim3(1), dim3(64), 0, stream,
                           tfs, bones, tinv, (int*)nullptr, ni);
        hipLaunchKernelGGL((deformer_cp_kernel<false>), dim3(nblk), dim3(256), 0, stream,
                           x, tfs, vox, tinv, (const int*)nullptr,
                           (float*)d_out, N, ni);
    }
}

// Round 11
// 211.974 us; speedup vs baseline: 1.2879x; 1.0835x over previous
//
#include <hip/hip_runtime.h>
#include <math.h>

#define NJ 25          // joints (voxel channels)
#define NJP 32         // padded channel stride in transposed layout (128B-aligned)
#define VD 32
#define VH 128
#define VW 128
#define TEMP 20.0f
#define NEGINF (-10000.0f)
#define DHW (VD*VH*VW)        // 524288
#define NCELL 4096            // 16^3 morton cells for the point sort
#define TINV_FLOATS 256

// workspace arena (floats): [tinv 256 | hist 4096 | offs 4096 | perm N | vt 16.78M]

// ---------------- sort helpers ----------------
__device__ __forceinline__ int cell_of(float v) {       // [-1,1] -> 0..15
    int c = (int)((v + 1.0f) * 8.0f);
    return min(max(c, 0), 15);
}
__device__ __forceinline__ int morton12(int ix, int iy, int iz) {
    int m = 0;
    #pragma unroll
    for (int b = 0; b < 4; ++b)
        m |= (((ix>>b)&1)<<(3*b)) | (((iy>>b)&1)<<(3*b+1)) | (((iz>>b)&1)<<(3*b+2));
    return m;
}

// ---------------- Kernel A: invert init-bone transforms + zero the sort histogram ----
__global__ void setup_kernel(const float* __restrict__ tfs,
                             const int* __restrict__ bones,
                             float* __restrict__ tinv,
                             int* __restrict__ hist, int ni) {
    int b = blockIdx.x, t = threadIdx.x;
    if (b == 0) {
        if (t >= ni) return;
        const float* T = tfs + (size_t)bones[t] * 16;
        double r00=T[0], r01=T[1], r02=T[2],  tx=T[3];
        double r10=T[4], r11=T[5], r12=T[6],  ty=T[7];
        double r20=T[8], r21=T[9], r22=T[10], tz=T[11];
        double c00 = r11*r22 - r12*r21;
        double c01 = r12*r20 - r10*r22;
        double c02 = r10*r21 - r11*r20;
        double det = r00*c00 + r01*c01 + r02*c02;
        double id  = 1.0/det;
        double i00 = c00*id;
        double i01 = (r02*r21 - r01*r22)*id;
        double i02 = (r01*r12 - r02*r11)*id;
        double i10 = c01*id;
        double i11 = (r00*r22 - r02*r20)*id;
        double i12 = (r02*r10 - r00*r12)*id;
        double i20 = c02*id;
        double i21 = (r01*r20 - r00*r21)*id;
        double i22 = (r00*r11 - r01*r10)*id;
        double itx = -(i00*tx + i01*ty + i02*tz);
        double ity = -(i10*tx + i11*ty + i12*tz);
        double itz = -(i20*tx + i21*ty + i22*tz);
        float* o = tinv + t*12;
        o[0]=(float)i00; o[1]=(float)i01; o[2] =(float)i02; o[3] =(float)itx;
        o[4]=(float)i10; o[5]=(float)i11; o[6] =(float)i12; o[7] =(float)ity;
        o[8]=(float)i20; o[9]=(float)i21; o[10]=(float)i22; o[11]=(float)itz;
    } else if (hist != nullptr) {
        int g = (b-1)*256 + t;
        if (g < NCELL) hist[g] = 0;
    }
}

// ---------------- Kernel B: transpose [J][D][H][W] -> [D][H][W][NJP] + fused hist ----
__global__ __launch_bounds__(256) void transpose_vox_kernel(const float* __restrict__ vox,
                                                            float* __restrict__ vt,
                                                            const float* __restrict__ x,
                                                            int* __restrict__ hist, int N) {
    __shared__ float lds[NJ*129];
    int row = blockIdx.x;                  // z*VH + y  (0..4095)
    int t = threadIdx.x;
    const float4* v4 = (const float4*)vox;
    for (int idx = t; idx < NJ*32; idx += 256) {       // 800 float4 loads
        int j  = idx >> 5;
        int x4 = idx & 31;
        float4 v = v4[(size_t)j*(DHW/4) + (size_t)row*32 + x4];
        float* l = &lds[j*129 + x4*4];
        l[0]=v.x; l[1]=v.y; l[2]=v.z; l[3]=v.w;
    }
    __syncthreads();
    float4* out4 = (float4*)(vt + (size_t)row * (VW*NJP));
    for (int idx = t; idx < (VW*NJP)/4; idx += 256) {  // 1024 float4 stores
        int xx = idx >> 3;
        int jq = (idx & 7) * 4;
        float4 o;
        o.x = (jq+0 < NJ) ? lds[(jq+0)*129 + xx] : 0.0f;
        o.y = (jq+1 < NJ) ? lds[(jq+1)*129 + xx] : 0.0f;
        o.z = (jq+2 < NJ) ? lds[(jq+2)*129 + xx] : 0.0f;
        o.w = (jq+3 < NJ) ? lds[(jq+3)*129 + xx] : 0.0f;
        out4[idx] = o;
    }
    // fused morton histogram (disjoint memory; setup_kernel zeroed hist earlier)
    for (int g = blockIdx.x*256 + t; g < N; g += gridDim.x*256) {
        int m = morton12(cell_of(x[g*3+0]), cell_of(x[g*3+1]), cell_of(x[g*3+2]));
        atomicAdd(&hist[m], 1);
    }
}

// ---------------- scan + scatter (counting sort) ----------------
__global__ __launch_bounds__(1024) void scan_kernel(const int* __restrict__ hist,
                                                    int* __restrict__ offs) {
    __shared__ int part[1024];
    int t = threadIdx.x;
    int4 h = ((const int4*)hist)[t];
    int s = h.x + h.y + h.z + h.w;
    part[t] = s;
    __syncthreads();
    for (int off = 1; off < 1024; off <<= 1) {
        int v = (t >= off) ? part[t-off] : 0;
        __syncthreads();
        part[t] += v;
        __syncthreads();
    }
    int excl = part[t] - s;
    offs[4*t+0] = excl;
    offs[4*t+1] = excl + h.x;
    offs[4*t+2] = excl + h.x + h.y;
    offs[4*t+3] = excl + h.x + h.y + h.z;
}
__global__ void scatter_kernel(const float* __restrict__ x, int* __restrict__ offs,
                               int* __restrict__ perm, int N) {
    int g = blockIdx.x*256 + threadIdx.x;
    if (g >= N) return;
    int m = morton12(cell_of(x[g*3+0]), cell_of(x[g*3+1]), cell_of(x[g*3+2]));
    int pos = atomicAdd(&offs[m], 1);
    perm[pos] = g;
}

// ---------------- Kernel C: 8-lane-group channel-parallel deformer ----------------
// One point per 8-LANE GROUP; lane l (=tid&7) owns channels 4l..4l+3 via float4.
// vs r9 (32-lane groups): per-pair setup amortized 22.5 -> 5.6 inst, butterfly
// 3 rounds (12 shfl) instead of 5 (20), corner loads 1 float4/lane (coalesced
// 128B per group). Kernel was 96% VALU-busy -> instruction count is the lever.
template<bool VT>
__global__ __launch_bounds__(256) void deformer_cp8_kernel(
        const float* __restrict__ x,
        const float* __restrict__ tfs,
        const float* __restrict__ vsrc,
        const float* __restrict__ tinv,
        const int* __restrict__ perm,
        float* __restrict__ out, int N, int ni) {
    int t = threadIdx.x;
    int l = t & 7;                         // lane in group

    // bijective XCD chunk-swizzle (nblk = 2048 -> r == 0, exact chunks)
    int nwg = gridDim.x;
    int q = nwg >> 3, r = nwg & 7;
    int xcd = blockIdx.x & 7, blk = blockIdx.x >> 3;
    int lb = (xcd < r ? xcd*(q+1) : r*(q+1) + (xcd-r)*q) + blk;

    int ns = lb*32 + (t >> 3);             // 32 points per 256-thread block
    if (ns >= N) return;
    int n = perm ? perm[ns] : ns;

    float px = x[n*3+0], py = x[n*3+1], pz = x[n*3+2];

    int c0 = l*4;                          // first channel of this lane
    // stage M rows 0-2 for this lane's 4 channels (clamped addr; pad ev=0 anyway)
    float M[4][12];
    #pragma unroll
    for (int cc = 0; cc < 4; ++cc) {
        const float* Mj = tfs + min(c0+cc, NJ-1)*16;
        #pragma unroll
        for (int r2 = 0; r2 < 12; ++r2) M[cc][r2] = Mj[r2];
    }
    bool v0 = (c0+0 < NJ), v1 = (c0+1 < NJ), v2 = (c0+2 < NJ), v3 = (c0+3 < NJ);

    float bestD = -3.0e38f; int bestIdx = 0; float bestInvs = 1.0f;
    float bE0 = 0.f, bE1 = 0.f, bE2 = 0.f, bE3 = 0.f;

    #pragma unroll 1
    for (int i = 0; i < ni; ++i) {
        const float* Ti = &tinv[i*12];     // loop-uniform -> scalar loads
        float cx = Ti[0]*px + Ti[1]*py + Ti[2] *pz + Ti[3];
        float cy = Ti[4]*px + Ti[5]*py + Ti[6] *pz + Ti[7];
        float cz = Ti[8]*px + Ti[9]*py + Ti[10]*pz + Ti[11];

        float gx = fminf(fmaxf((cx + 1.0f) * (0.5f*(VW-1)), 0.0f), (float)(VW-1));
        float gy = fminf(fmaxf((cy + 1.0f) * (0.5f*(VH-1)), 0.0f), (float)(VH-1));
        float gz = fminf(fmaxf((cz + 1.0f) * (0.5f*(VD-1)), 0.0f), (float)(VD-1));
        int x0 = (int)gx, y0 = (int)gy, z0 = (int)gz;
        int x1 = min(x0+1, VW-1), y1 = min(y0+1, VH-1), z1 = min(z0+1, VD-1);
        float fx = gx - (float)x0, fy = gy - (float)y0, fz = gz - (float)z0;
        float ax = 1.0f - fx, ay = 1.0f - fy, az = 1.0f - fz;
        float w000 = ax*ay*az, w001 = fx*ay*az, w010 = ax*fy*az, w011 = fx*fy*az;
        float w100 = ax*ay*fz, w101 = fx*ay*fz, w110 = ax*fy*fz, w111 = fx*fy*fz;

        float vv0, vv1, vv2, vv3;
        if (VT) {
            int o   = ((z0*VH + y0)*VW + x0)*NJP + c0;   // float4-aligned, coalesced
            int dz  = (z1 - z0) * (VH*VW*NJP);
            int dy  = (y1 - y0) * (VW*NJP);
            int dxo = (x1 - x0) * NJP;
            float4 a000 = *(const float4*)&vsrc[o];
            float4 a001 = *(const float4*)&vsrc[o+dxo];
            float4 a010 = *(const float4*)&vsrc[o+dy];
            float4 a011 = *(const float4*)&vsrc[o+dy+dxo];
            float4 a100 = *(const float4*)&vsrc[o+dz];
            float4 a101 = *(const float4*)&vsrc[o+dz+dxo];
            float4 a110 = *(const float4*)&vsrc[o+dz+dy];
            float4 a111 = *(const float4*)&vsrc[o+dz+dy+dxo];
            vv0 = a000.x*w000 + a001.x*w001 + a010.x*w010 + a011.x*w011
                + a100.x*w100 + a101.x*w101 + a110.x*w110 + a111.x*w111;
            vv1 = a000.y*w000 + a001.y*w001 + a010.y*w010 + a011.y*w011
                + a100.y*w100 + a101.y*w101 + a110.y*w110 + a111.y*w111;
            vv2 = a000.z*w000 + a001.z*w001 + a010.z*w010 + a011.z*w011
                + a100.z*w100 + a101.z*w101 + a110.z*w110 + a111.z*w111;
            vv3 = a000.w*w000 + a001.w*w001 + a010.w*w010 + a011.w*w011
                + a100.w*w100 + a101.w*w101 + a110.w*w110 + a111.w*w111;
        } else {
            int cell = (z0*VH + y0)*VW + x0;
            int dz  = (z1 - z0) * (VH*VW);
            int dy  = (y1 - y0) * VW;
            int dxo = (x1 - x0);
            float vvs[4];
            #pragma unroll
            for (int cc = 0; cc < 4; ++cc) {
                const float* vj = vsrc + (size_t)min(c0+cc, NJ-1)*DHW + cell;
                vvs[cc] = vj[0]*w000       + vj[dxo]*w001
                        + vj[dy]*w010      + vj[dy+dxo]*w011
                        + vj[dz]*w100      + vj[dz+dxo]*w101
                        + vj[dz+dy]*w110   + vj[dz+dy+dxo]*w111;
            }
            vv0 = vvs[0]; vv1 = vvs[1]; vv2 = vvs[2]; vv3 = vvs[3];
        }

        float ev0 = v0 ? __expf(TEMP * vv0) : 0.0f;
        float ev1 = v1 ? __expf(TEMP * vv1) : 0.0f;
        float ev2 = v2 ? __expf(TEMP * vv2) : 0.0f;
        float ev3 = v3 ? __expf(TEMP * vv3) : 0.0f;

        float rs = (ev0 + ev1) + (ev2 + ev3);
        float mx0 = M[0][0]*cx + M[0][1]*cy + M[0][2] *cz + M[0][3];
        float my0 = M[0][4]*cx + M[0][5]*cy + M[0][6] *cz + M[0][7];
        float mz0 = M[0][8]*cx + M[0][9]*cy + M[0][10]*cz + M[0][11];
        float mx1 = M[1][0]*cx + M[1][1]*cy + M[1][2] *cz + M[1][3];
        float my1 = M[1][4]*cx + M[1][5]*cy + M[1][6] *cz + M[1][7];
        float mz1 = M[1][8]*cx + M[1][9]*cy + M[1][10]*cz + M[1][11];
        float mx2 = M[2][0]*cx + M[2][1]*cy + M[2][2] *cz + M[2][3];
        float my2 = M[2][4]*cx + M[2][5]*cy + M[2][6] *cz + M[2][7];
        float mz2 = M[2][8]*cx + M[2][9]*cy + M[2][10]*cz + M[2][11];
        float mx3 = M[3][0]*cx + M[3][1]*cy + M[3][2] *cz + M[3][3];
        float my3 = M[3][4]*cx + M[3][5]*cy + M[3][6] *cz + M[3][7];
        float mz3 = M[3][8]*cx + M[3][9]*cy + M[3][10]*cz + M[3][11];
        float rx = ev0*mx0 + ev1*mx1 + ev2*mx2 + ev3*mx3;
        float ry = ev0*my0 + ev1*my1 + ev2*my2 + ev3*my3;
        float rz = ev0*mz0 + ev1*mz1 + ev2*mz2 + ev3*mz3;

        #pragma unroll
        for (int mk = 1; mk < 8; mk <<= 1) {     // 3-round butterfly over 8 lanes
            rs += __shfl_xor(rs, mk, 8);
            rx += __shfl_xor(rx, mk, 8);
            ry += __shfl_xor(ry, mk, 8);
            rz += __shfl_xor(rz, mk, 8);
        }
        float invs = 1.0f / rs;
        float dxp = rx*invs - px, dyp = ry*invs - py, dzp = rz*invs - pz;
        float err = sqrtf(dxp*dxp + dyp*dyp + dzp*dzp);
        float d = (err < 0.1f) ? -err : NEGINF;

        if (d > bestD) {                   // strict > + ascending i = first-index tie-break
            bestD = d; bestIdx = i; bestInvs = invs;
            bE0 = ev0; bE1 = ev1; bE2 = ev2; bE3 = ev3;
        }
    }

    float* o_d = out;                       // [N]
    float* o_f = out + N;                   // [N,15]
    float* o_m = out + (size_t)N*16;        // [N]
    float* o_w = out + (size_t)N*17;        // [N,3]
    if (l < 4) {
        int kb = c0;                        // channels 4l..4l+3, skip k>=15
        float e0 = bE0*bestInvs, e1 = bE1*bestInvs, e2 = bE2*bestInvs, e3 = bE3*bestInvs;
        float* of = &o_f[(size_t)n*15 + kb];
        if (kb+0 < 15) of[0] = e0;
        if (kb+1 < 15) of[1] = e1;
        if (kb+2 < 15) of[2] = e2;
        if (kb+3 < 15) of[3] = e3;
    } else if (l == 4) {
        o_d[n] = bestD;
        o_m[n] = (bestD > -9999.0f) ? 1.0f : 0.0f;
    } else {
        int rr = l - 5;                     // 0,1,2 -> winner xc rows
        const float* Tr = &tinv[bestIdx*12 + rr*4];
        o_w[(size_t)n*3 + rr] = Tr[0]*px + Tr[1]*py + Tr[2]*pz + Tr[3];
    }
}

extern "C" void kernel_launch(void* const* d_in, const int* in_sizes, int n_in,
                              void* d_out, int out_size, void* d_ws, size_t ws_size,
                              hipStream_t stream) {
    const float* x     = (const float*)d_in[0];   // [1,N,3]
    const float* tfs   = (const float*)d_in[1];   // [1,25,4,4]
    const float* vox   = (const float*)d_in[2];   // [1,25,32,128,128]
    const int*   bones = (const int*)  d_in[3];   // [14]
    int N  = in_sizes[0] / 3;
    int ni = in_sizes[3];

    float* ws = (float*)d_ws;
    // arena (floats): [tinv 256 | hist 4096 | offs 4096 | perm N | vt 16.78M]
    size_t vt_off    = (size_t)TINV_FLOATS + NCELL*2 + (size_t)N;
    size_t vt_floats = (size_t)DHW * NJP;
    size_t need_all  = vt_off + vt_floats;

    float* tinv = ws;
    int*   hist = (int*)(ws + TINV_FLOATS);
    int*   offs = hist + NCELL;
    int*   perm = offs + NCELL;
    float* vt   = ws + vt_off;

    bool useVT = ws_size >= need_all * sizeof(float);
    int nblk = (N + 31) / 32;               // 32 points per 256-thread block

    if (useVT) {
        hipLaunchKernelGGL(setup_kernel, dim3(1 + NCELL/256), dim3(256), 0, stream,
                           tfs, bones, tinv, hist, ni);
        hipLaunchKernelGGL(transpose_vox_kernel, dim3(VD*VH), dim3(256), 0, stream,
                           vox, vt, x, hist, N);
        hipLaunchKernelGGL(scan_kernel, dim3(1), dim3(1024), 0, stream, hist, offs);
        hipLaunchKernelGGL(scatter_kernel, dim3((N+255)/256), dim3(256), 0, stream,
                           x, offs, perm, N);
        hipLaunchKernelGGL((deformer_cp8_kernel<true>), dim3(nblk), dim3(256), 0, stream,
                           x, tfs, vt, tinv, perm, (float*)d_out, N, ni);
    } else {
        hipLaunchKernelGGL(setup_kernel, dim3(1), dim3(64), 0, stream,
                           tfs, bones, tinv, (int*)nullptr, ni);
        hipLaunchKernelGGL((deformer_cp8_kernel<false>), dim3(nblk), dim3(256), 0, stream,
                           x, tfs, vox, tinv, (const int*)nullptr,
                           (float*)d_out, N, ni);
    }
}